// Round 1
// baseline (1536.458 us; speedup 1.0000x reference)
//
#include <hip/hip_runtime.h>

#define NTH  512
#define XLEN 368
#define NF   112

// ---- LDS layout (float offsets) ----
#define IMG_OFF 0          // 114x114 zero-halo img          [0,12996)
#define IMG_LD  114
#define XSP_OFF 12996      // zero-padded x, capacity 1008   [12996,14004)
#define XSP_CAP 1008
#define H1_OFF  14004      // 6 x 58 x 58 zero-halo          [14004,34188)
#define QLO_OFF 34188      // 14 ints (per filter-oct k-lo)
#define QHI_OFF 34202      // 14 ints
#define SEL_OFF 34216      // 112 ints (IMG_SELECT)
#define TOT_F   34328      // 137312 bytes dynamic LDS

// time-aliased late-phase regions
#define H2_OFF  0          // 12 x 30 x 30 zero-halo [0,10800)
#define H3_OFF  10800      // 12 x 16 x 16 zero-halo [10800,13872)
#define H4_OFF  0          // 588 (12x7x7, flatten order)
#define FC1_OFF 600        // 48
#define LG_OFF  652        // 4

__global__ void wavelet_bounds(const float* __restrict__ ww, int K,
                               int* __restrict__ bnd) {
  int f = blockIdx.x * blockDim.x + threadIdx.x;
  if (f >= NF) return;
  const float* wr = ww + (size_t)f * K;
  int lo = K, hi = 0;
  for (int k = 0; k < K; ++k) {
    if (wr[k] != 0.f) { lo = min(lo, k); hi = k + 1; }
  }
  bnd[2 * f] = lo;
  bnd[2 * f + 1] = hi;
}

__device__ __forceinline__ void conv4acc(const float (&p)[4][4],
                                         const float (&w9)[9],
                                         float (&acc)[4]) {
  #pragma unroll
  for (int dy = 0; dy < 2; ++dy)
    #pragma unroll
    for (int dx = 0; dx < 2; ++dx) {
      float a = 0.f;
      #pragma unroll
      for (int dr = 0; dr < 3; ++dr)
        #pragma unroll
        for (int dc = 0; dc < 3; ++dc)
          a += p[dy + dr][dx + dc] * w9[dr * 3 + dc];
      acc[dy * 2 + dx] += a;
    }
}

__global__ __launch_bounds__(NTH) void fused_convnet(
    const float* __restrict__ x, const float* __restrict__ ww,
    const int* __restrict__ bnd, int K,
    const float* __restrict__ c1w, const float* __restrict__ c1b,
    const float* __restrict__ c2w, const float* __restrict__ c2b,
    const float* __restrict__ c3w, const float* __restrict__ c3b,
    const float* __restrict__ c4w, const float* __restrict__ c4b,
    const float* __restrict__ f1w, const float* __restrict__ f1b,
    const float* __restrict__ f2w, const float* __restrict__ f2b,
    float* __restrict__ out) {
  extern __shared__ float sf[];
  int* si = (int*)sf;
  const int b = blockIdx.x;
  const int tid = threadIdx.x;
  const int pad = (K - 1) >> 1;
  const int xplen = XLEN + K - 1;

  // ---- phase 0: init (zero img+h1 halos, stage padded x, tables) ----
  for (int i = tid; i < 12996; i += NTH) sf[IMG_OFF + i] = 0.f;
  for (int i = tid; i < 20184; i += NTH) sf[H1_OFF + i] = 0.f;
  {
    int lim = xplen < XSP_CAP ? xplen : XSP_CAP;
    for (int i = tid; i < lim; i += NTH) {
      int xi = i - pad;
      sf[XSP_OFF + i] = (xi >= 0 && xi < XLEN) ? x[(size_t)b * XLEN + xi] : 0.f;
    }
  }
  if (tid < NF)
    si[SEL_OFF + tid] = (tid == NF - 1)
        ? (XLEN - 1)
        : (int)((double)tid * ((double)(XLEN - 1) / (double)(NF - 1)));
  if (tid < 14) {
    int lo = K, hi = 0;
    #pragma unroll
    for (int i = 0; i < 8; ++i) {
      int f = tid * 8 + i;
      lo = min(lo, bnd[2 * f]);
      hi = max(hi, bnd[2 * f + 1]);
    }
    si[QLO_OFF + tid] = lo;
    si[QHI_OFF + tid] = hi;
  }
  __syncthreads();

  // ---- CWT at the 112 selected positions ----
  // items: (k-chunk, filter-oct, j-quad); wave-uniform filter oct,
  // k-chunking load-balances the 9x spread in filter lengths.
  {
    const int nck = (K + 31) >> 5;
    const int nit = nck * 392;  // 392 = 14 octs * 28 j-quads
    for (int it = tid; it < nit; it += NTH) {
      int ck = it / 392;
      int rem = it - ck * 392;
      int fo = rem / 28;
      int jq = rem - fo * 28;
      int klo = max(si[QLO_OFF + fo], ck << 5);
      int khi = min(si[QHI_OFF + fo], (ck << 5) + 32);
      if (klo >= khi) continue;
      const int f0 = fo << 3, j0 = jq << 2;
      const int b0 = si[SEL_OFF + j0 + 0];
      const int b1 = si[SEL_OFF + j0 + 1];
      const int b2 = si[SEL_OFF + j0 + 2];
      const int b3 = si[SEL_OFF + j0 + 3];
      float acc[8][4];
      #pragma unroll
      for (int i = 0; i < 8; ++i)
        #pragma unroll
        for (int jj = 0; jj < 4; ++jj) acc[i][jj] = 0.f;
      const float* wb = ww + (size_t)f0 * K;
      for (int k = klo; k < khi; ++k) {
        float xv0 = sf[XSP_OFF + b0 + k];
        float xv1 = sf[XSP_OFF + b1 + k];
        float xv2 = sf[XSP_OFF + b2 + k];
        float xv3 = sf[XSP_OFF + b3 + k];
        #pragma unroll
        for (int i = 0; i < 8; ++i) {
          float wv = wb[(size_t)i * K + k];
          acc[i][0] += wv * xv0;
          acc[i][1] += wv * xv1;
          acc[i][2] += wv * xv2;
          acc[i][3] += wv * xv3;
        }
      }
      #pragma unroll
      for (int i = 0; i < 8; ++i) {
        float* dst = &sf[IMG_OFF + (f0 + i + 1) * IMG_LD + (j0 + 1)];
        #pragma unroll
        for (int jj = 0; jj < 4; ++jj) atomicAdd(dst + jj, acc[i][jj]);
      }
    }
  }
  __syncthreads();

  // ---- conv1(1->6) + relu + pool: img 112x112 -> h1 6x56x56 ----
  for (int it = tid; it < 3136; it += NTH) {
    int pr = it / 56, pc = it - pr * 56;
    int r0 = pr * 2, c0 = pc * 2;
    float p[4][4];
    #pragma unroll
    for (int i = 0; i < 4; ++i)
      #pragma unroll
      for (int j2 = 0; j2 < 4; ++j2)
        p[i][j2] = sf[IMG_OFF + (r0 + i) * IMG_LD + (c0 + j2)];
    #pragma unroll
    for (int oc = 0; oc < 6; ++oc) {
      float w9[9];
      #pragma unroll
      for (int t = 0; t < 9; ++t) w9[t] = c1w[oc * 9 + t];
      float acc[4] = {c1b[oc], c1b[oc], c1b[oc], c1b[oc]};
      conv4acc(p, w9, acc);
      float m = fmaxf(fmaxf(acc[0], acc[1]), fmaxf(acc[2], acc[3]));
      sf[H1_OFF + oc * 3364 + (pr + 1) * 58 + (pc + 1)] = fmaxf(m, 0.f);
    }
  }
  __syncthreads();

  // ---- zero h2+h3 halo region (aliases dead img/xsp) ----
  for (int i = tid; i < 13872; i += NTH) sf[i] = 0.f;
  __syncthreads();

  // ---- conv2(6->12) + relu + pool: 56x56 -> h2 12x28x28 ----
  for (int it = tid; it < 2352; it += NTH) {  // 3 oc-quads * 784 pos
    int ob = it / 784;
    int rem = it - ob * 784;
    int pr = rem / 28, pc = rem - pr * 28;
    int oc0 = ob * 4;
    float acc[4][4];
    #pragma unroll
    for (int q = 0; q < 4; ++q) {
      float bia = c2b[oc0 + q];
      #pragma unroll
      for (int t = 0; t < 4; ++t) acc[q][t] = bia;
    }
    for (int ic = 0; ic < 6; ++ic) {
      float p[4][4];
      #pragma unroll
      for (int i = 0; i < 4; ++i)
        #pragma unroll
        for (int j2 = 0; j2 < 4; ++j2)
          p[i][j2] = sf[H1_OFF + ic * 3364 + (pr * 2 + i) * 58 + (pc * 2 + j2)];
      #pragma unroll
      for (int q = 0; q < 4; ++q) {
        const float* wp = c2w + ((size_t)(oc0 + q) * 6 + ic) * 9;
        float w9[9];
        #pragma unroll
        for (int t = 0; t < 9; ++t) w9[t] = wp[t];
        conv4acc(p, w9, acc[q]);
      }
    }
    #pragma unroll
    for (int q = 0; q < 4; ++q) {
      float m = fmaxf(fmaxf(acc[q][0], acc[q][1]), fmaxf(acc[q][2], acc[q][3]));
      sf[H2_OFF + (oc0 + q) * 900 + (pr + 1) * 30 + (pc + 1)] = fmaxf(m, 0.f);
    }
  }
  __syncthreads();

  // ---- conv3(12->12) + relu + pool: 28x28 -> h3 12x14x14 ----
  for (int it = tid; it < 1176; it += NTH) {  // 6 oc-pairs * 196 pos
    int ob = it / 196;
    int rem = it - ob * 196;
    int pr = rem / 14, pc = rem - pr * 14;
    int oc0 = ob * 2;
    float acc[2][4];
    #pragma unroll
    for (int q = 0; q < 2; ++q) {
      float bia = c3b[oc0 + q];
      #pragma unroll
      for (int t = 0; t < 4; ++t) acc[q][t] = bia;
    }
    for (int ic = 0; ic < 12; ++ic) {
      float p[4][4];
      #pragma unroll
      for (int i = 0; i < 4; ++i)
        #pragma unroll
        for (int j2 = 0; j2 < 4; ++j2)
          p[i][j2] = sf[H2_OFF + ic * 900 + (pr * 2 + i) * 30 + (pc * 2 + j2)];
      #pragma unroll
      for (int q = 0; q < 2; ++q) {
        const float* wp = c3w + ((size_t)(oc0 + q) * 12 + ic) * 9;
        float w9[9];
        #pragma unroll
        for (int t = 0; t < 9; ++t) w9[t] = wp[t];
        conv4acc(p, w9, acc[q]);
      }
    }
    #pragma unroll
    for (int q = 0; q < 2; ++q) {
      float m = fmaxf(fmaxf(acc[q][0], acc[q][1]), fmaxf(acc[q][2], acc[q][3]));
      sf[H3_OFF + (oc0 + q) * 256 + (pr + 1) * 16 + (pc + 1)] = fmaxf(m, 0.f);
    }
  }
  __syncthreads();

  // ---- conv4(12->12) + relu + pool: 14x14 -> h4 12x7x7 (flat) ----
  for (int it = tid; it < 294; it += NTH) {  // 6 oc-pairs * 49 pos
    int ob = it / 49;
    int rem = it - ob * 49;
    int pr = rem / 7, pc = rem - pr * 7;
    int oc0 = ob * 2;
    float acc[2][4];
    #pragma unroll
    for (int q = 0; q < 2; ++q) {
      float bia = c4b[oc0 + q];
      #pragma unroll
      for (int t = 0; t < 4; ++t) acc[q][t] = bia;
    }
    for (int ic = 0; ic < 12; ++ic) {
      float p[4][4];
      #pragma unroll
      for (int i = 0; i < 4; ++i)
        #pragma unroll
        for (int j2 = 0; j2 < 4; ++j2)
          p[i][j2] = sf[H3_OFF + ic * 256 + (pr * 2 + i) * 16 + (pc * 2 + j2)];
      #pragma unroll
      for (int q = 0; q < 2; ++q) {
        const float* wp = c4w + ((size_t)(oc0 + q) * 12 + ic) * 9;
        float w9[9];
        #pragma unroll
        for (int t = 0; t < 9; ++t) w9[t] = wp[t];
        conv4acc(p, w9, acc[q]);
      }
    }
    #pragma unroll
    for (int q = 0; q < 2; ++q) {
      float m = fmaxf(fmaxf(acc[q][0], acc[q][1]), fmaxf(acc[q][2], acc[q][3]));
      sf[H4_OFF + (oc0 + q) * 49 + pr * 7 + pc] = fmaxf(m, 0.f);
    }
  }
  __syncthreads();

  // ---- fc1 (588 -> 48), one wave per output, coalesced weight reads ----
  {
    int wv = tid >> 6, ln = tid & 63;
    for (int o = wv; o < 48; o += 8) {
      float s = 0.f;
      for (int i = ln; i < 588; i += 64)
        s += sf[H4_OFF + i] * f1w[(size_t)o * 588 + i];
      #pragma unroll
      for (int off = 32; off > 0; off >>= 1) s += __shfl_down(s, off);
      if (ln == 0) sf[FC1_OFF + o] = fmaxf(s + f1b[o], 0.f);
    }
  }
  __syncthreads();

  // ---- fc2 (48 -> 4) ----
  if (tid < 4) {
    float s = f2b[tid];
    for (int i = 0; i < 48; ++i) s += sf[FC1_OFF + i] * f2w[tid * 48 + i];
    sf[LG_OFF + tid] = s;
  }
  __syncthreads();

  // ---- softmax ----
  if (tid < 4) {
    float l0 = sf[LG_OFF + 0], l1 = sf[LG_OFF + 1];
    float l2 = sf[LG_OFF + 2], l3 = sf[LG_OFF + 3];
    float m = fmaxf(fmaxf(l0, l1), fmaxf(l2, l3));
    float e0 = expf(l0 - m), e1 = expf(l1 - m);
    float e2 = expf(l2 - m), e3 = expf(l3 - m);
    float ssum = e0 + e1 + e2 + e3;
    float mine = expf(sf[LG_OFF + tid] - m);
    out[(size_t)b * 4 + tid] = mine / ssum;
  }
}

extern "C" void kernel_launch(void* const* d_in, const int* in_sizes, int n_in,
                              void* d_out, int out_size, void* d_ws,
                              size_t ws_size, hipStream_t stream) {
  const float* x   = (const float*)d_in[0];
  const float* ww  = (const float*)d_in[1];
  const float* c1w = (const float*)d_in[2];
  const float* c1b = (const float*)d_in[3];
  const float* c2w = (const float*)d_in[4];
  const float* c2b = (const float*)d_in[5];
  const float* c3w = (const float*)d_in[6];
  const float* c3b = (const float*)d_in[7];
  const float* c4w = (const float*)d_in[8];
  const float* c4b = (const float*)d_in[9];
  const float* f1w = (const float*)d_in[10];
  const float* f1b = (const float*)d_in[11];
  const float* f2w = (const float*)d_in[12];
  const float* f2b = (const float*)d_in[13];
  float* out = (float*)d_out;

  const int B = in_sizes[0] / XLEN;
  const int K = in_sizes[1] / NF;  // 561 for this problem
  int* bnd = (int*)d_ws;           // 224 ints

  hipLaunchKernelGGL(wavelet_bounds, dim3(1), dim3(128), 0, stream, ww, K, bnd);

  const size_t smem = (size_t)TOT_F * sizeof(float);  // 137312 B
  hipFuncSetAttribute((const void*)fused_convnet,
                      hipFuncAttributeMaxDynamicSharedMemorySize, (int)smem);
  hipLaunchKernelGGL(fused_convnet, dim3(B), dim3(NTH), smem, stream,
                     x, ww, bnd, K, c1w, c1b, c2w, c2b, c3w, c3b, c4w, c4b,
                     f1w, f1b, f2w, f2b, out);
}

// Round 2
// 1178.258 us; speedup vs baseline: 1.3040x; 1.3040x over previous
//
#include <hip/hip_runtime.h>

#define NTH  1024
#define XLEN 368
#define NF   112

// ---- LDS layout (float offsets) ----
#define IMG_OFF 0          // 114x114 zero-halo img          [0,12996)
#define IMG_LD  114
#define XSP_OFF 12996      // zero-padded x, capacity 1008   [12996,14004)
#define H1_OFF  14004      // 6 x 58 x 58 zero-halo          [14004,34188)
#define QLO_OFF 34188      // 14 ints (per filter-oct k-lo)
#define QHI_OFF 34202      // 14 ints
#define TOT_F   34328      // 137312 bytes dynamic LDS

// time-aliased late-phase regions
#define H2_OFF  0          // 12 x 30 x 30 zero-halo [0,10800)
#define H3_OFF  10800      // 12 x 16 x 16 zero-halo [10800,13872)
#define BUF_OFF 14004      // conv3/conv4 pre-pool buffers (<=9408)
#define H4_OFF  0          // 588 (12x7x7, flatten order) — h2 dead by then
#define FC1_OFF 600        // 48
#define LG_OFF  652        // 4

__global__ void wavelet_bounds(const float* __restrict__ ww, int K,
                               int* __restrict__ bnd) {
  int f = blockIdx.x;
  int l = threadIdx.x;
  const float* wr = ww + (size_t)f * K;
  int lo = K, hi = -1;
  for (int k = l; k < K; k += 64) {
    if (wr[k] != 0.f) { lo = min(lo, k); hi = max(hi, k); }
  }
  #pragma unroll
  for (int off = 32; off; off >>= 1) {
    lo = min(lo, __shfl_down(lo, off));
    hi = max(hi, __shfl_down(hi, off));
  }
  if (l == 0) { bnd[2 * f] = lo; bnd[2 * f + 1] = hi + 1; }
}

__device__ __forceinline__ void conv4acc(const float (&p)[4][4],
                                         const float (&w9)[9],
                                         float (&acc)[4]) {
  #pragma unroll
  for (int dy = 0; dy < 2; ++dy)
    #pragma unroll
    for (int dx = 0; dx < 2; ++dx) {
      float a = 0.f;
      #pragma unroll
      for (int dr = 0; dr < 3; ++dr)
        #pragma unroll
        for (int dc = 0; dc < 3; ++dc)
          a += p[dy + dr][dx + dc] * w9[dr * 3 + dc];
      acc[dy * 2 + dx] += a;
    }
}

__global__ __launch_bounds__(NTH) void fused_convnet(
    const float* __restrict__ x, const float* __restrict__ ww,
    const int* __restrict__ bnd, int K,
    const float* __restrict__ c1w, const float* __restrict__ c1b,
    const float* __restrict__ c2w, const float* __restrict__ c2b,
    const float* __restrict__ c3w, const float* __restrict__ c3b,
    const float* __restrict__ c4w, const float* __restrict__ c4b,
    const float* __restrict__ f1w, const float* __restrict__ f1b,
    const float* __restrict__ f2w, const float* __restrict__ f2b,
    float* __restrict__ out) {
  extern __shared__ float sf[];
  int* si = (int*)sf;
  const int b = blockIdx.x;
  const int tid = threadIdx.x;
  const int pad = (K - 1) >> 1;
  const int xplen = XLEN + K - 1;  // 928 for K=561

  // ---- phase 0: init ----
  for (int i = tid; i < 12996; i += NTH) sf[IMG_OFF + i] = 0.f;
  for (int i = tid; i < 20184; i += NTH) sf[H1_OFF + i] = 0.f;
  for (int i = tid; i < xplen; i += NTH) {
    int xi = i - pad;
    sf[XSP_OFF + i] = (xi >= 0 && xi < XLEN) ? x[(size_t)b * XLEN + xi] : 0.f;
  }
  if (tid < 14) {
    int lo = K, hi = 0;
    #pragma unroll
    for (int i = 0; i < 8; ++i) {
      int f = tid * 8 + i;
      lo = min(lo, bnd[2 * f]);
      hi = max(hi, bnd[2 * f + 1]);
    }
    si[QLO_OFF + tid] = lo;
    si[QHI_OFF + tid] = hi;
  }
  __syncthreads();

  // ---- phase 1: CWT at 112 selected positions ----
  // wave owns (filter-oct, k-chunk64); lane owns 2 positions (l, 64+l).
  // readfirstlane makes oct/bounds scalar -> weight reads become s_loads.
  {
    const int wid = __builtin_amdgcn_readfirstlane(tid >> 6);
    const int lane = tid & 63;
    const int p0 = lane;
    const bool has1 = (64 + lane) < NF;
    const int p1 = has1 ? (64 + lane) : (NF - 1);
    const int b0 = (p0 == NF - 1) ? (XLEN - 1)
                 : (int)((double)p0 * ((double)(XLEN - 1) / (double)(NF - 1)));
    const int b1 = (p1 == NF - 1) ? (XLEN - 1)
                 : (int)((double)p1 * ((double)(XLEN - 1) / (double)(NF - 1)));
    const int nck = (K + 63) >> 6;
    const int nit = 14 * nck;
    for (int it = wid; it < nit; it += 16) {
      int o = it / nck, c = it - o * nck;
      int klo = __builtin_amdgcn_readfirstlane(si[QLO_OFF + o]);
      int khi = __builtin_amdgcn_readfirstlane(si[QHI_OFF + o]);
      klo = max(klo, c << 6);
      khi = min(khi, (c << 6) + 64);
      if (klo >= khi) continue;
      const float* wb = ww + (size_t)(o << 3) * K;
      float a0[8], a1[8];
      #pragma unroll
      for (int i = 0; i < 8; ++i) { a0[i] = 0.f; a1[i] = 0.f; }
      for (int k = klo; k < khi; ++k) {
        float xv0 = sf[XSP_OFF + b0 + k];
        float xv1 = sf[XSP_OFF + b1 + k];
        #pragma unroll
        for (int i = 0; i < 8; ++i) {
          float wv = wb[(size_t)i * K + k];
          a0[i] = fmaf(wv, xv0, a0[i]);
          a1[i] = fmaf(wv, xv1, a1[i]);
        }
      }
      const int row0 = (o << 3) + 1;
      #pragma unroll
      for (int i = 0; i < 8; ++i) {
        atomicAdd(&sf[IMG_OFF + (row0 + i) * IMG_LD + (p0 + 1)], a0[i]);
        if (has1)
          atomicAdd(&sf[IMG_OFF + (row0 + i) * IMG_LD + (p1 + 1)], a1[i]);
      }
    }
  }
  __syncthreads();

  // ---- phase 2: conv1(1->6)+relu+pool: img 112x112 -> h1 6x56x56 ----
  for (int it = tid; it < 3136; it += NTH) {
    int pr = it / 56, pc = it - pr * 56;
    int r0 = pr * 2, c0 = pc * 2;
    float p[4][4];
    #pragma unroll
    for (int i = 0; i < 4; ++i)
      #pragma unroll
      for (int j2 = 0; j2 < 4; ++j2)
        p[i][j2] = sf[IMG_OFF + (r0 + i) * IMG_LD + (c0 + j2)];
    #pragma unroll
    for (int oc = 0; oc < 6; ++oc) {
      float w9[9];
      #pragma unroll
      for (int t = 0; t < 9; ++t) w9[t] = c1w[oc * 9 + t];
      float acc[4] = {c1b[oc], c1b[oc], c1b[oc], c1b[oc]};
      conv4acc(p, w9, acc);
      float m = fmaxf(fmaxf(acc[0], acc[1]), fmaxf(acc[2], acc[3]));
      sf[H1_OFF + oc * 3364 + (pr + 1) * 58 + (pc + 1)] = fmaxf(m, 0.f);
    }
  }
  __syncthreads();

  // ---- phase 3: zero h2+h3 halo region (aliases dead img/xsp) ----
  for (int i = tid; i < 13872; i += NTH) sf[i] = 0.f;
  __syncthreads();

  // ---- phase 4: conv2(6->12)+relu+pool: h1 -> h2 12x28x28 ----
  // uniform ob loop -> scalar weight loads; thread owns one pooled pos.
  {
    int pos = tid;
    int pr = pos / 28, pc = pos - pr * 28;
    #pragma unroll
    for (int ob = 0; ob < 2; ++ob) {
      if (pos < 784) {
        int oc0 = ob * 6;
        float acc[6][4];
        #pragma unroll
        for (int q = 0; q < 6; ++q) {
          float bia = c2b[oc0 + q];
          #pragma unroll
          for (int t = 0; t < 4; ++t) acc[q][t] = bia;
        }
        for (int ic = 0; ic < 6; ++ic) {
          float p[4][4];
          #pragma unroll
          for (int i = 0; i < 4; ++i)
            #pragma unroll
            for (int j2 = 0; j2 < 4; ++j2)
              p[i][j2] =
                  sf[H1_OFF + ic * 3364 + (pr * 2 + i) * 58 + (pc * 2 + j2)];
          #pragma unroll
          for (int q = 0; q < 6; ++q) {
            const float* wp = c2w + ((size_t)(oc0 + q) * 6 + ic) * 9;
            float w9[9];
            #pragma unroll
            for (int t = 0; t < 9; ++t) w9[t] = wp[t];
            conv4acc(p, w9, acc[q]);
          }
        }
        #pragma unroll
        for (int q = 0; q < 6; ++q) {
          float m = fmaxf(fmaxf(acc[q][0], acc[q][1]),
                          fmaxf(acc[q][2], acc[q][3]));
          sf[H2_OFF + (oc0 + q) * 900 + (pr + 1) * 30 + (pc + 1)] =
              fmaxf(m, 0.f);
        }
      }
    }
  }
  __syncthreads();

  // ---- phase 5: conv3(12->12) conv-points 28x28 -> buf ----
  if (tid < 784) {
    int r = tid / 28, c = tid - r * 28;
    float acc[12];
    #pragma unroll
    for (int oc = 0; oc < 12; ++oc) acc[oc] = c3b[oc];
    for (int ic = 0; ic < 12; ++ic) {
      float p9[9];
      #pragma unroll
      for (int dr = 0; dr < 3; ++dr)
        #pragma unroll
        for (int dc = 0; dc < 3; ++dc)
          p9[dr * 3 + dc] = sf[H2_OFF + ic * 900 + (r + dr) * 30 + (c + dc)];
      #pragma unroll
      for (int oc = 0; oc < 12; ++oc) {
        const float* wp = c3w + ((size_t)oc * 12 + ic) * 9;
        float a = 0.f;
        #pragma unroll
        for (int t = 0; t < 9; ++t) a = fmaf(p9[t], wp[t], a);
        acc[oc] += a;
      }
    }
    #pragma unroll
    for (int oc = 0; oc < 12; ++oc)
      sf[BUF_OFF + oc * 784 + r * 28 + c] = acc[oc];
  }
  __syncthreads();

  // ---- phase 6: pool3 -> h3 12x16x16 halo ----
  for (int it = tid; it < 2352; it += NTH) {
    int oc = it / 196;
    int rem = it - oc * 196;
    int pr = rem / 14, pc = rem - pr * 14;
    const float* bp = &sf[BUF_OFF + oc * 784 + (pr * 2) * 28 + pc * 2];
    float m = fmaxf(fmaxf(bp[0], bp[1]), fmaxf(bp[28], bp[29]));
    sf[H3_OFF + oc * 256 + (pr + 1) * 16 + (pc + 1)] = fmaxf(m, 0.f);
  }
  __syncthreads();

  // ---- phase 7: conv4(12->12) conv-points 14x14 -> buf ----
  if (tid < 196) {
    int r = tid / 14, c = tid - r * 14;
    float acc[12];
    #pragma unroll
    for (int oc = 0; oc < 12; ++oc) acc[oc] = c4b[oc];
    for (int ic = 0; ic < 12; ++ic) {
      float p9[9];
      #pragma unroll
      for (int dr = 0; dr < 3; ++dr)
        #pragma unroll
        for (int dc = 0; dc < 3; ++dc)
          p9[dr * 3 + dc] = sf[H3_OFF + ic * 256 + (r + dr) * 16 + (c + dc)];
      #pragma unroll
      for (int oc = 0; oc < 12; ++oc) {
        const float* wp = c4w + ((size_t)oc * 12 + ic) * 9;
        float a = 0.f;
        #pragma unroll
        for (int t = 0; t < 9; ++t) a = fmaf(p9[t], wp[t], a);
        acc[oc] += a;
      }
    }
    #pragma unroll
    for (int oc = 0; oc < 12; ++oc)
      sf[BUF_OFF + oc * 196 + r * 14 + c] = acc[oc];
  }
  __syncthreads();

  // ---- phase 8: pool4 -> h4 flat 588 (12x7x7 NCHW flatten) ----
  if (tid < 588) {
    int oc = tid / 49;
    int rem = tid - oc * 49;
    int pr = rem / 7, pc = rem - pr * 7;
    const float* bp = &sf[BUF_OFF + oc * 196 + (pr * 2) * 14 + pc * 2];
    float m = fmaxf(fmaxf(bp[0], bp[1]), fmaxf(bp[14], bp[15]));
    sf[H4_OFF + oc * 49 + pr * 7 + pc] = fmaxf(m, 0.f);
  }
  __syncthreads();

  // ---- phase 9: fc1 (588 -> 48), one wave per output ----
  {
    int wv = tid >> 6, ln = tid & 63;
    for (int o = wv; o < 48; o += 16) {
      float s = 0.f;
      for (int i = ln; i < 588; i += 64)
        s += sf[H4_OFF + i] * f1w[(size_t)o * 588 + i];
      #pragma unroll
      for (int off = 32; off > 0; off >>= 1) s += __shfl_down(s, off);
      if (ln == 0) sf[FC1_OFF + o] = fmaxf(s + f1b[o], 0.f);
    }
  }
  __syncthreads();

  // ---- phase 10: fc2 (48 -> 4) + softmax ----
  if (tid < 4) {
    float s = f2b[tid];
    for (int i = 0; i < 48; ++i) s += sf[FC1_OFF + i] * f2w[tid * 48 + i];
    sf[LG_OFF + tid] = s;
  }
  __syncthreads();
  if (tid < 4) {
    float l0 = sf[LG_OFF + 0], l1 = sf[LG_OFF + 1];
    float l2 = sf[LG_OFF + 2], l3 = sf[LG_OFF + 3];
    float m = fmaxf(fmaxf(l0, l1), fmaxf(l2, l3));
    float e0 = expf(l0 - m), e1 = expf(l1 - m);
    float e2 = expf(l2 - m), e3 = expf(l3 - m);
    float ssum = e0 + e1 + e2 + e3;
    out[(size_t)b * 4 + tid] = expf(sf[LG_OFF + tid] - m) / ssum;
  }
}

extern "C" void kernel_launch(void* const* d_in, const int* in_sizes, int n_in,
                              void* d_out, int out_size, void* d_ws,
                              size_t ws_size, hipStream_t stream) {
  const float* x   = (const float*)d_in[0];
  const float* ww  = (const float*)d_in[1];
  const float* c1w = (const float*)d_in[2];
  const float* c1b = (const float*)d_in[3];
  const float* c2w = (const float*)d_in[4];
  const float* c2b = (const float*)d_in[5];
  const float* c3w = (const float*)d_in[6];
  const float* c3b = (const float*)d_in[7];
  const float* c4w = (const float*)d_in[8];
  const float* c4b = (const float*)d_in[9];
  const float* f1w = (const float*)d_in[10];
  const float* f1b = (const float*)d_in[11];
  const float* f2w = (const float*)d_in[12];
  const float* f2b = (const float*)d_in[13];
  float* out = (float*)d_out;

  const int B = in_sizes[0] / XLEN;
  const int K = in_sizes[1] / NF;  // 561 for this problem
  int* bnd = (int*)d_ws;           // 224 ints

  hipLaunchKernelGGL(wavelet_bounds, dim3(NF), dim3(64), 0, stream, ww, K, bnd);

  const size_t smem = (size_t)TOT_F * sizeof(float);  // 137312 B
  hipFuncSetAttribute((const void*)fused_convnet,
                      hipFuncAttributeMaxDynamicSharedMemorySize, (int)smem);
  hipLaunchKernelGGL(fused_convnet, dim3(B), dim3(NTH), smem, stream,
                     x, ww, bnd, K, c1w, c1b, c2w, c2b, c3w, c3b, c4w, c4b,
                     f1w, f1b, f2w, f2b, out);
}

// Round 3
// 552.290 us; speedup vs baseline: 2.7820x; 2.1334x over previous
//
#include <hip/hip_runtime.h>

#define NTH  1024
#define XLEN 368
#define NF   112

typedef short bh8 __attribute__((ext_vector_type(8)));
typedef float fv4 __attribute__((ext_vector_type(4)));

// ---- LDS layout (float offsets) ----
#define IMG_OFF 0          // 114x114 zero-halo img          [0,12996)
#define IMG_LD  114
#define XSP_OFF 12996      // zero-padded x, capacity 1008   [12996,14004)
#define XSP_CAP 1008
#define H1_OFF  14004      // 6 x 58 x 58 zero-halo          [14004,34188)
#define TOT_F   34188      // 136752 bytes dynamic LDS

// time-aliased late-phase regions
#define H2_OFF  0          // 12 x 30 x 30 zero-halo [0,10800)
#define H3_OFF  10800      // 12 x 16 x 16 zero-halo [10800,13872)
#define BUF_OFF 14004      // conv3/conv4 pre-pool buffers (<=9408)
#define H4_OFF  0          // 588 (12x7x7, flatten order)
#define FC1_OFF 600        // 48
#define LG_OFF  652        // 4

__device__ __forceinline__ unsigned short bf16_bits(float v) {
  union { __bf16 b; unsigned short u; } c;
  c.b = (__bf16)v;
  return c.u;
}

// Pre-arrange wavelet bank into MFMA A-fragment order (bf16):
// Aarr[((ft*nks + ks)*64 + lane)*8 + e] = bf16(ww[ft*16 + (lane&15)][ks*32 + 8*(lane>>4) + e])
__global__ void prep_A(const float* __restrict__ ww, int K, int nks,
                       unsigned short* __restrict__ Aarr) {
  int idx = blockIdx.x * 256 + threadIdx.x;
  int total = 7 * nks * 64;
  if (idx >= total) return;
  int lane = idx & 63;
  int fk = idx >> 6;
  int ks = fk % nks, ft = fk / nks;
  int frow = ft * 16 + (lane & 15);
  int k0 = ks * 32 + 8 * (lane >> 4);
  union { bh8 s; unsigned short h[8]; } o;
  #pragma unroll
  for (int e = 0; e < 8; ++e) {
    int k = k0 + e;
    int kk = k < K ? k : K - 1;
    float v = ww[(size_t)frow * K + kk];
    o.h[e] = bf16_bits(k < K ? v : 0.f);
  }
  ((bh8*)Aarr)[idx] = o.s;
}

__device__ __forceinline__ void conv4acc(const float (&p)[4][4],
                                         const float (&w9)[9],
                                         float (&acc)[4]) {
  #pragma unroll
  for (int dy = 0; dy < 2; ++dy)
    #pragma unroll
    for (int dx = 0; dx < 2; ++dx) {
      float a = 0.f;
      #pragma unroll
      for (int dr = 0; dr < 3; ++dr)
        #pragma unroll
        for (int dc = 0; dc < 3; ++dc)
          a += p[dy + dr][dx + dc] * w9[dr * 3 + dc];
      acc[dy * 2 + dx] += a;
    }
}

template <bool PRE>
__global__ __launch_bounds__(NTH) void fused_convnet(
    const float* __restrict__ x, const float* __restrict__ ww,
    const unsigned short* __restrict__ Aarr, int K, int nks,
    const float* __restrict__ c1w, const float* __restrict__ c1b,
    const float* __restrict__ c2w, const float* __restrict__ c2b,
    const float* __restrict__ c3w, const float* __restrict__ c3b,
    const float* __restrict__ c4w, const float* __restrict__ c4b,
    const float* __restrict__ f1w, const float* __restrict__ f1b,
    const float* __restrict__ f2w, const float* __restrict__ f2b,
    float* __restrict__ out) {
  extern __shared__ float sf[];
  const int b = blockIdx.x;
  const int tid = threadIdx.x;
  const int pad = (K - 1) >> 1;

  // ---- phase 0: init (vectorized zero + stage padded x) ----
  {
    float4* z = (float4*)(sf + IMG_OFF);
    for (int i = tid; i < 3249; i += NTH) z[i] = float4{0.f, 0.f, 0.f, 0.f};
    float4* z1 = (float4*)(sf + H1_OFF);
    for (int i = tid; i < 5046; i += NTH) z1[i] = float4{0.f, 0.f, 0.f, 0.f};
  }
  for (int i = tid; i < XSP_CAP; i += NTH) {
    int xi = i - pad;
    sf[XSP_OFF + i] = (xi >= 0 && xi < XLEN) ? x[(size_t)b * XLEN + xi] : 0.f;
  }
  __syncthreads();

  // ---- phase 1: CWT via MFMA: img[f][j] = sum_k ww[f][k] * xsp[sel_j + k]
  {
    const int wid = tid >> 6, lane = tid & 63;
    if (wid < 14) {
      const int jt = wid % 7, fg = wid / 7;
      const int ft0 = fg * 4;
      const int nft = fg ? 3 : 4;
      const int jcol = jt * 16 + (lane & 15);
      const int selj = (jcol == NF - 1)
          ? (XLEN - 1)
          : (int)((double)jcol * ((double)(XLEN - 1) / (double)(NF - 1)));
      const int koff = (lane >> 4) * 8;
      fv4 acc[4];
      #pragma unroll
      for (int t = 0; t < 4; ++t)
        #pragma unroll
        for (int r = 0; r < 4; ++r) acc[t][r] = 0.f;
      for (int ks = 0; ks < nks; ++ks) {
        const int k0 = (ks << 5) + koff;
        // B-fragment: 8 consecutive xsp values per lane, f32 -> bf16
        union { bh8 s; __bf16 h[8]; } bu;
        #pragma unroll
        for (int e = 0; e < 8; ++e)
          bu.h[e] = (__bf16)sf[XSP_OFF + selj + k0 + e];
        if (PRE) {
          #pragma unroll
          for (int t = 0; t < 4; ++t)
            if (t < nft) {
              bh8 af = ((const bh8*)Aarr)[((size_t)(ft0 + t) * nks + ks) * 64 + lane];
              acc[t] = __builtin_amdgcn_mfma_f32_16x16x32_bf16(af, bu.s,
                                                               acc[t], 0, 0, 0);
            }
        } else {
          #pragma unroll
          for (int t = 0; t < 4; ++t)
            if (t < nft) {
              const int frow = (ft0 + t) * 16 + (lane & 15);
              union { bh8 s; __bf16 h[8]; } au;
              #pragma unroll
              for (int e = 0; e < 8; ++e) {
                int k = k0 + e;
                int kk = k < K ? k : K - 1;
                float v = ww[(size_t)frow * K + kk];
                au.h[e] = (__bf16)(k < K ? v : 0.f);
              }
              acc[t] = __builtin_amdgcn_mfma_f32_16x16x32_bf16(au.s, bu.s,
                                                               acc[t], 0, 0, 0);
            }
        }
      }
      // C-write: col=lane&15, row=(lane>>4)*4+reg  (m89-verified layout)
      const int col = jt * 16 + (lane & 15) + 1;
      #pragma unroll
      for (int t = 0; t < 4; ++t)
        if (t < nft) {
          const int fbase = (ft0 + t) * 16 + (lane >> 4) * 4 + 1;
          #pragma unroll
          for (int r = 0; r < 4; ++r)
            sf[IMG_OFF + (fbase + r) * IMG_LD + col] = acc[t][r];
        }
    }
  }
  __syncthreads();

  // ---- phase 2: conv1(1->6)+relu+pool: img 112x112 -> h1 6x56x56 ----
  for (int it = tid; it < 3136; it += NTH) {
    int pr = it / 56, pc = it - pr * 56;
    int r0 = pr * 2, c0 = pc * 2;
    float p[4][4];
    #pragma unroll
    for (int i = 0; i < 4; ++i)
      #pragma unroll
      for (int j2 = 0; j2 < 4; ++j2)
        p[i][j2] = sf[IMG_OFF + (r0 + i) * IMG_LD + (c0 + j2)];
    #pragma unroll
    for (int oc = 0; oc < 6; ++oc) {
      float w9[9];
      #pragma unroll
      for (int t = 0; t < 9; ++t) w9[t] = c1w[oc * 9 + t];
      float acc[4] = {c1b[oc], c1b[oc], c1b[oc], c1b[oc]};
      conv4acc(p, w9, acc);
      float m = fmaxf(fmaxf(acc[0], acc[1]), fmaxf(acc[2], acc[3]));
      sf[H1_OFF + oc * 3364 + (pr + 1) * 58 + (pc + 1)] = fmaxf(m, 0.f);
    }
  }
  __syncthreads();

  // ---- phase 3: zero h2+h3 region (aliases dead img/xsp) ----
  {
    float4* z = (float4*)sf;
    for (int i = tid; i < 3468; i += NTH) z[i] = float4{0.f, 0.f, 0.f, 0.f};
  }
  __syncthreads();

  // ---- phase 4: conv2(6->12)+relu+pool: h1 -> h2 12x28x28 ----
  {
    int pos = tid;
    int pr = pos / 28, pc = pos - pr * 28;
    #pragma unroll
    for (int ob = 0; ob < 2; ++ob) {
      if (pos < 784) {
        int oc0 = ob * 6;
        float acc[6][4];
        #pragma unroll
        for (int q = 0; q < 6; ++q) {
          float bia = c2b[oc0 + q];
          #pragma unroll
          for (int t = 0; t < 4; ++t) acc[q][t] = bia;
        }
        for (int ic = 0; ic < 6; ++ic) {
          float p[4][4];
          #pragma unroll
          for (int i = 0; i < 4; ++i)
            #pragma unroll
            for (int j2 = 0; j2 < 4; ++j2)
              p[i][j2] =
                  sf[H1_OFF + ic * 3364 + (pr * 2 + i) * 58 + (pc * 2 + j2)];
          #pragma unroll
          for (int q = 0; q < 6; ++q) {
            const float* wp = c2w + ((size_t)(oc0 + q) * 6 + ic) * 9;
            float w9[9];
            #pragma unroll
            for (int t = 0; t < 9; ++t) w9[t] = wp[t];
            conv4acc(p, w9, acc[q]);
          }
        }
        #pragma unroll
        for (int q = 0; q < 6; ++q) {
          float m = fmaxf(fmaxf(acc[q][0], acc[q][1]),
                          fmaxf(acc[q][2], acc[q][3]));
          sf[H2_OFF + (oc0 + q) * 900 + (pr + 1) * 30 + (pc + 1)] =
              fmaxf(m, 0.f);
        }
      }
    }
  }
  __syncthreads();

  // ---- phase 5: conv3(12->12) conv-points 28x28 -> buf ----
  if (tid < 784) {
    int r = tid / 28, c = tid - r * 28;
    float acc[12];
    #pragma unroll
    for (int oc = 0; oc < 12; ++oc) acc[oc] = c3b[oc];
    for (int ic = 0; ic < 12; ++ic) {
      float p9[9];
      #pragma unroll
      for (int dr = 0; dr < 3; ++dr)
        #pragma unroll
        for (int dc = 0; dc < 3; ++dc)
          p9[dr * 3 + dc] = sf[H2_OFF + ic * 900 + (r + dr) * 30 + (c + dc)];
      #pragma unroll
      for (int oc = 0; oc < 12; ++oc) {
        const float* wp = c3w + ((size_t)oc * 12 + ic) * 9;
        float a = 0.f;
        #pragma unroll
        for (int t = 0; t < 9; ++t) a = fmaf(p9[t], wp[t], a);
        acc[oc] += a;
      }
    }
    #pragma unroll
    for (int oc = 0; oc < 12; ++oc)
      sf[BUF_OFF + oc * 784 + r * 28 + c] = acc[oc];
  }
  __syncthreads();

  // ---- phase 6: pool3 -> h3 12x16x16 halo ----
  for (int it = tid; it < 2352; it += NTH) {
    int oc = it / 196;
    int rem = it - oc * 196;
    int pr = rem / 14, pc = rem - pr * 14;
    const float* bp = &sf[BUF_OFF + oc * 784 + (pr * 2) * 28 + pc * 2];
    float m = fmaxf(fmaxf(bp[0], bp[1]), fmaxf(bp[28], bp[29]));
    sf[H3_OFF + oc * 256 + (pr + 1) * 16 + (pc + 1)] = fmaxf(m, 0.f);
  }
  __syncthreads();

  // ---- phase 7: conv4(12->12) conv-points 14x14 -> buf ----
  if (tid < 196) {
    int r = tid / 14, c = tid - r * 14;
    float acc[12];
    #pragma unroll
    for (int oc = 0; oc < 12; ++oc) acc[oc] = c4b[oc];
    for (int ic = 0; ic < 12; ++ic) {
      float p9[9];
      #pragma unroll
      for (int dr = 0; dr < 3; ++dr)
        #pragma unroll
        for (int dc = 0; dc < 3; ++dc)
          p9[dr * 3 + dc] = sf[H3_OFF + ic * 256 + (r + dr) * 16 + (c + dc)];
      #pragma unroll
      for (int oc = 0; oc < 12; ++oc) {
        const float* wp = c4w + ((size_t)oc * 12 + ic) * 9;
        float a = 0.f;
        #pragma unroll
        for (int t = 0; t < 9; ++t) a = fmaf(p9[t], wp[t], a);
        acc[oc] += a;
      }
    }
    #pragma unroll
    for (int oc = 0; oc < 12; ++oc)
      sf[BUF_OFF + oc * 196 + r * 14 + c] = acc[oc];
  }
  __syncthreads();

  // ---- phase 8: pool4 -> h4 flat 588 (12x7x7 NCHW flatten) ----
  if (tid < 588) {
    int oc = tid / 49;
    int rem = tid - oc * 49;
    int pr = rem / 7, pc = rem - pr * 7;
    const float* bp = &sf[BUF_OFF + oc * 196 + (pr * 2) * 14 + pc * 2];
    float m = fmaxf(fmaxf(bp[0], bp[1]), fmaxf(bp[14], bp[15]));
    sf[H4_OFF + oc * 49 + pr * 7 + pc] = fmaxf(m, 0.f);
  }
  __syncthreads();

  // ---- phase 9: fc1 (588 -> 48), one wave per output ----
  {
    int wv = tid >> 6, ln = tid & 63;
    for (int o = wv; o < 48; o += 16) {
      float s = 0.f;
      for (int i = ln; i < 588; i += 64)
        s += sf[H4_OFF + i] * f1w[(size_t)o * 588 + i];
      #pragma unroll
      for (int off = 32; off > 0; off >>= 1) s += __shfl_down(s, off);
      if (ln == 0) sf[FC1_OFF + o] = fmaxf(s + f1b[o], 0.f);
    }
  }
  __syncthreads();

  // ---- phase 10: fc2 (48 -> 4) + softmax ----
  if (tid < 4) {
    float s = f2b[tid];
    for (int i = 0; i < 48; ++i) s += sf[FC1_OFF + i] * f2w[tid * 48 + i];
    sf[LG_OFF + tid] = s;
  }
  __syncthreads();
  if (tid < 4) {
    float l0 = sf[LG_OFF + 0], l1 = sf[LG_OFF + 1];
    float l2 = sf[LG_OFF + 2], l3 = sf[LG_OFF + 3];
    float m = fmaxf(fmaxf(l0, l1), fmaxf(l2, l3));
    float e0 = expf(l0 - m), e1 = expf(l1 - m);
    float e2 = expf(l2 - m), e3 = expf(l3 - m);
    float ssum = e0 + e1 + e2 + e3;
    out[(size_t)b * 4 + tid] = expf(sf[LG_OFF + tid] - m) / ssum;
  }
}

extern "C" void kernel_launch(void* const* d_in, const int* in_sizes, int n_in,
                              void* d_out, int out_size, void* d_ws,
                              size_t ws_size, hipStream_t stream) {
  const float* x   = (const float*)d_in[0];
  const float* ww  = (const float*)d_in[1];
  const float* c1w = (const float*)d_in[2];
  const float* c1b = (const float*)d_in[3];
  const float* c2w = (const float*)d_in[4];
  const float* c2b = (const float*)d_in[5];
  const float* c3w = (const float*)d_in[6];
  const float* c3b = (const float*)d_in[7];
  const float* c4w = (const float*)d_in[8];
  const float* c4b = (const float*)d_in[9];
  const float* f1w = (const float*)d_in[10];
  const float* f1b = (const float*)d_in[11];
  const float* f2w = (const float*)d_in[12];
  const float* f2b = (const float*)d_in[13];
  float* out = (float*)d_out;

  const int B = in_sizes[0] / XLEN;
  const int K = in_sizes[1] / NF;  // 561
  const int nks = (K + 31) / 32;   // 18

  const size_t abytes = (size_t)7 * nks * 64 * 8 * sizeof(unsigned short);
  const bool pre = ws_size >= abytes;
  unsigned short* Aarr = (unsigned short*)d_ws;

  const size_t smem = (size_t)TOT_F * sizeof(float);  // 136752 B

  if (pre) {
    int items = 7 * nks * 64;
    hipLaunchKernelGGL(prep_A, dim3((items + 255) / 256), dim3(256), 0, stream,
                       ww, K, nks, Aarr);
    hipFuncSetAttribute((const void*)fused_convnet<true>,
                        hipFuncAttributeMaxDynamicSharedMemorySize, (int)smem);
    hipLaunchKernelGGL(fused_convnet<true>, dim3(B), dim3(NTH), smem, stream,
                       x, ww, Aarr, K, nks, c1w, c1b, c2w, c2b, c3w, c3b,
                       c4w, c4b, f1w, f1b, f2w, f2b, out);
  } else {
    hipFuncSetAttribute((const void*)fused_convnet<false>,
                        hipFuncAttributeMaxDynamicSharedMemorySize, (int)smem);
    hipLaunchKernelGGL(fused_convnet<false>, dim3(B), dim3(NTH), smem, stream,
                       x, ww, Aarr, K, nks, c1w, c1b, c2w, c2b, c3w, c3b,
                       c4w, c4b, f1w, f1b, f2w, f2b, out);
  }
}